// Round 1
// baseline (664.646 us; speedup 1.0000x reference)
//
#include <hip/hip_runtime.h>
#include <stdint.h>

typedef unsigned short u16;
typedef unsigned int   u32;
typedef __attribute__((ext_vector_type(8))) __bf16 bf16x8;
typedef __attribute__((ext_vector_type(4))) float  f32x4;

#define MFMA_16x16x32_BF16(a, b, c) __builtin_amdgcn_mfma_f32_16x16x32_bf16((a), (b), (c), 0, 0, 0)

__device__ __forceinline__ u16 f2b(float f) {
    u32 u = __builtin_bit_cast(u32, f);
    u32 r = (u + 0x7FFFu + ((u >> 16) & 1u)) >> 16;
    return (u16)r;
}
__device__ __forceinline__ float b2f(u16 h) {
    u32 u = ((u32)h) << 16;
    return __builtin_bit_cast(float, u);
}

// async 16B/lane global->LDS. LDS dest is wave-uniform base + lane*16.
__device__ __forceinline__ void gload_lds16(const void* g, void* l) {
    __builtin_amdgcn_global_load_lds(
        (const __attribute__((address_space(1))) u32*)g,
        (__attribute__((address_space(3))) u32*)l,
        16, 0, 0);
}

// ---------------------------------------------------------------------------
// cast fp32 -> bf16 for x (8388608), w_qkv (12582912), w_proj (4194304)
// ---------------------------------------------------------------------------
__global__ __launch_bounds__(256) void cast3(const float* __restrict__ x,
                                             const float* __restrict__ wq,
                                             const float* __restrict__ wp,
                                             u16* __restrict__ xb,
                                             u16* __restrict__ wqb,
                                             u16* __restrict__ wpb) {
    const int n1 = 8388608, n2 = 12582912, n3 = 4194304;
    const int total4 = (n1 + n2 + n3) / 4;
    for (int i = blockIdx.x * blockDim.x + threadIdx.x; i < total4;
         i += gridDim.x * blockDim.x) {
        int e = i * 4;
        const float* src; u16* dst; int off;
        if (e < n1)            { src = x;  dst = xb;  off = e; }
        else if (e < n1 + n2)  { src = wq; dst = wqb; off = e - n1; }
        else                   { src = wp; dst = wpb; off = e - n1 - n2; }
        float4 v = *(const float4*)(src + off);
        ushort4 o;
        o.x = f2b(v.x); o.y = f2b(v.y); o.z = f2b(v.z); o.w = f2b(v.w);
        *(ushort4*)(dst + off) = o;
    }
}

// ---------------------------------------------------------------------------
// C[M,N] = A[M,K] * Bt[N,K]^T  (bf16 in, fp32 accumulate).
// 128x128 tile, BK=64, 256 threads (4 waves, 64x64 each, 4x4 16x16x32 frags).
// OUT_BF16: 1 -> bf16 store, 0 -> fp32 store.
// ---------------------------------------------------------------------------
template <int OUT_BF16>
__global__ __launch_bounds__(256) void gemm_bt(const u16* __restrict__ A,
                                               const u16* __restrict__ Bt,
                                               void* __restrict__ Cout,
                                               int M, int N, int K) {
    __shared__ u16 Al[128 * 64];
    __shared__ u16 Bl[128 * 64];
    const int tid  = threadIdx.x;
    const int w    = tid >> 6;
    const int lane = tid & 63;
    const int quad = lane >> 4;
    const int l16  = lane & 15;
    const int m0 = blockIdx.y * 128;
    const int n0 = blockIdx.x * 128;
    const int wm = (w >> 1) * 64;
    const int wn = (w & 1) * 64;

    f32x4 acc[4][4];
#pragma unroll
    for (int i = 0; i < 4; i++) {
#pragma unroll
        for (int j = 0; j < 4; j++) acc[i][j] = (f32x4){0.f, 0.f, 0.f, 0.f};
    }

    const u16* Abase = A + (size_t)(m0 + (tid >> 3)) * K + (tid & 7) * 8;
    const u16* Bbase = Bt + (size_t)(n0 + (tid >> 3)) * K + (tid & 7) * 8;
    char* AlB = (char*)Al + w * 1024;
    char* BlB = (char*)Bl + w * 1024;

    for (int k0 = 0; k0 < K; k0 += 64) {
        __syncthreads();
#pragma unroll
        for (int i = 0; i < 4; i++) {
            gload_lds16(Abase + (size_t)i * 32 * K + k0, AlB + i * 4096);
            gload_lds16(Bbase + (size_t)i * 32 * K + k0, BlB + i * 4096);
        }
        __syncthreads();
#pragma unroll
        for (int ks = 0; ks < 2; ks++) {
            bf16x8 Af[4];
#pragma unroll
            for (int mi = 0; mi < 4; mi++)
                Af[mi] = *(const bf16x8*)&Al[(wm + mi * 16 + l16) * 64 + ks * 32 + quad * 8];
#pragma unroll
            for (int ni = 0; ni < 4; ni++) {
                bf16x8 Bf = *(const bf16x8*)&Bl[(wn + ni * 16 + l16) * 64 + ks * 32 + quad * 8];
#pragma unroll
                for (int mi = 0; mi < 4; mi++)
                    acc[mi][ni] = MFMA_16x16x32_BF16(Af[mi], Bf, acc[mi][ni]);
            }
        }
    }

    // epilogue: C/D layout col = l16, row = quad*4 + reg
    const int row0 = m0 + wm + quad * 4;
    const int col0 = n0 + wn + l16;
#pragma unroll
    for (int mi = 0; mi < 4; mi++) {
#pragma unroll
        for (int r = 0; r < 4; r++) {
            size_t rowb = (size_t)(row0 + mi * 16 + r) * N;
#pragma unroll
            for (int ni = 0; ni < 4; ni++) {
                float v = acc[mi][ni][r];
                if (OUT_BF16) ((u16*)Cout)[rowb + col0 + ni * 16] = f2b(v);
                else          ((float*)Cout)[rowb + col0 + ni * 16] = v;
            }
        }
    }
}

// ---------------------------------------------------------------------------
// RoPE(q,k) + split/transpose qkv[B,T,3,H,Dh] -> Q,K (roped), V in [B,H,T,Dh]
// one block per (b,t), 256 threads
// ---------------------------------------------------------------------------
__global__ __launch_bounds__(256) void rope_split(const u16* __restrict__ qkv,
                                                  u16* __restrict__ Q,
                                                  u16* __restrict__ K,
                                                  u16* __restrict__ V) {
    const int bt = blockIdx.x;          // 0..4095
    const int b = bt >> 11, t = bt & 2047;
    const u16* row = qkv + (size_t)bt * 6144;
    const int tid = threadIdx.x;

    // q/k rope: 2*16*64 = 2048 (head, pair) items
#pragma unroll
    for (int it = 0; it < 8; it++) {
        int p   = it * 256 + tid;
        int qk  = p >> 10;          // 0=q, 1=k (uniform per it)
        int rem = p & 1023;
        int h   = rem >> 6;
        int i   = rem & 63;
        float x1 = b2f(row[qk * 2048 + h * 128 + i]);
        float x2 = b2f(row[qk * 2048 + h * 128 + i + 64]);
        // inv_freq = 10000^(-i/64)
        float inv = expf(-0.14391156f * (float)i);
        float th  = (float)t * inv;
        float s, c;
        sincosf(th, &s, &c);
        float o1 = x1 * c - x2 * s;
        float o2 = x2 * c + x1 * s;
        u16* dst = (qk ? K : Q) + ((size_t)((b * 16 + h) * 2048 + t)) * 128;
        dst[i]      = f2b(o1);
        dst[i + 64] = f2b(o2);
    }
    // v copy: 16*128 = 2048 elems
#pragma unroll
    for (int it = 0; it < 8; it++) {
        int e = it * 256 + tid;
        int h = e >> 7, d = e & 127;
        V[((size_t)((b * 16 + h) * 2048 + t)) * 128 + d] = row[4096 + h * 128 + d];
    }
}

// ---------------------------------------------------------------------------
// causal flash attention. grid (16 qtiles, 32 bh), 256 threads.
// Q-tile 128 rows (32/wave); K/V tiles of 64 staged in LDS; online softmax.
// O written bf16 to [B,T,H*Dh] (GEMM-ready for out-proj).
// ---------------------------------------------------------------------------
__global__ __launch_bounds__(256) void attn(const u16* __restrict__ Q,
                                            const u16* __restrict__ Kg,
                                            const u16* __restrict__ Vg,
                                            u16* __restrict__ O) {
    __shared__ u16 Kl[64 * 128];     // [k][d]
    __shared__ u16 Vt[128 * 64];     // [d][k]  (transposed V)
    __shared__ u16 Pl[4 * 32 * 64];  // per-wave P scratch

    const int tid  = threadIdx.x;
    const int w    = tid >> 6;
    const int lane = tid & 63;
    const int quad = lane >> 4;
    const int l16  = lane & 15;
    const int qt = blockIdx.x;       // 0..15
    const int bh = blockIdx.y;       // 0..31
    const int q0 = qt * 128;
    const size_t base = (size_t)bh * 2048 * 128;
    const u16* Qb = Q + base;
    const u16* Kb = Kg + base;
    const u16* Vb = Vg + base;

    // Q fragments (A-operand layout: m = l16, k = quad*8 + j)
    bf16x8 Qf[2][4];
#pragma unroll
    for (int mi = 0; mi < 2; mi++) {
#pragma unroll
        for (int kk = 0; kk < 4; kk++)
            Qf[mi][kk] = *(const bf16x8*)&Qb[(size_t)(q0 + w * 32 + mi * 16 + l16) * 128 + kk * 32 + quad * 8];
    }

    f32x4 Oacc[2][8];
#pragma unroll
    for (int mi = 0; mi < 2; mi++) {
#pragma unroll
        for (int ni = 0; ni < 8; ni++) Oacc[mi][ni] = (f32x4){0.f, 0.f, 0.f, 0.f};
    }
    float mrow[2][4], lrow[2][4];
#pragma unroll
    for (int mi = 0; mi < 2; mi++) {
#pragma unroll
        for (int r = 0; r < 4; r++) { mrow[mi][r] = -INFINITY; lrow[mi][r] = 0.f; }
    }

    const float scale = 0.08838834764831845f;   // 1/sqrt(128)
    const int nkt = 2 * qt + 2;                 // k-tiles through the diagonal

    for (int kt = 0; kt < nkt; kt++) {
        const int kt0 = kt * 64;
        __syncthreads();
        // stage K tile [64][128] via async global->LDS
        {
            const u16* src = Kb + (size_t)(kt0 + (tid >> 4)) * 128 + (tid & 15) * 8;
            char* dst = (char*)Kl + w * 1024;
#pragma unroll
            for (int i = 0; i < 4; i++)
                gload_lds16(src + (size_t)i * 16 * 128, dst + i * 4096);
        }
        // stage V transposed -> Vt[d][k]
        {
#pragma unroll
            for (int i = 0; i < 4; i++) {
                int k  = i * 16 + (tid >> 4);
                int d0 = (tid & 15) * 8;
                uint4 pack = *(const uint4*)(Vb + (size_t)(kt0 + k) * 128 + d0);
                const u16* tp = (const u16*)&pack;
#pragma unroll
                for (int j = 0; j < 8; j++) Vt[(d0 + j) * 64 + k] = tp[j];
            }
        }
        __syncthreads();

        // S = Q K^T   (S[mi][ni]: rows quad*4+r, cols l16)
        f32x4 S[2][4];
#pragma unroll
        for (int ni = 0; ni < 4; ni++) {
#pragma unroll
            for (int mi = 0; mi < 2; mi++) S[mi][ni] = (f32x4){0.f, 0.f, 0.f, 0.f};
#pragma unroll
            for (int kk = 0; kk < 4; kk++) {
                bf16x8 Kf = *(const bf16x8*)&Kl[(ni * 16 + l16) * 128 + kk * 32 + quad * 8];
#pragma unroll
                for (int mi = 0; mi < 2; mi++)
                    S[mi][ni] = MFMA_16x16x32_BF16(Qf[mi][kk], Kf, S[mi][ni]);
            }
        }

        // scale + causal mask + online softmax
#pragma unroll
        for (int mi = 0; mi < 2; mi++) {
            float tmax[4] = {-1e30f, -1e30f, -1e30f, -1e30f};
#pragma unroll
            for (int ni = 0; ni < 4; ni++) {
                int kg = kt0 + ni * 16 + l16;
#pragma unroll
                for (int r = 0; r < 4; r++) {
                    int qg = q0 + w * 32 + mi * 16 + quad * 4 + r;
                    float s = S[mi][ni][r] * scale;
                    s = (kg > qg) ? -1e30f : s;
                    S[mi][ni][r] = s;
                    tmax[r] = fmaxf(tmax[r], s);
                }
            }
#pragma unroll
            for (int r = 0; r < 4; r++) {
#pragma unroll
                for (int off = 1; off < 16; off <<= 1)
                    tmax[r] = fmaxf(tmax[r], __shfl_xor(tmax[r], off));
            }
            float alpha[4];
#pragma unroll
            for (int r = 0; r < 4; r++) {
                float mnew = fmaxf(mrow[mi][r], tmax[r]);
                alpha[r] = __expf(mrow[mi][r] - mnew);
                mrow[mi][r] = mnew;
            }
            float tsum[4] = {0.f, 0.f, 0.f, 0.f};
#pragma unroll
            for (int ni = 0; ni < 4; ni++) {
#pragma unroll
                for (int r = 0; r < 4; r++) {
                    float p = __expf(S[mi][ni][r] - mrow[mi][r]);
                    S[mi][ni][r] = p;
                    tsum[r] += p;
                }
            }
#pragma unroll
            for (int r = 0; r < 4; r++) {
#pragma unroll
                for (int off = 1; off < 16; off <<= 1)
                    tsum[r] += __shfl_xor(tsum[r], off);
                lrow[mi][r] = lrow[mi][r] * alpha[r] + tsum[r];
            }
#pragma unroll
            for (int ni = 0; ni < 8; ni++) {
#pragma unroll
                for (int r = 0; r < 4; r++) Oacc[mi][ni][r] *= alpha[r];
            }
            // P -> LDS (bf16) for layout change C/D -> A-operand
#pragma unroll
            for (int ni = 0; ni < 4; ni++) {
#pragma unroll
                for (int r = 0; r < 4; r++)
                    Pl[w * 2048 + (mi * 16 + quad * 4 + r) * 64 + ni * 16 + l16] = f2b(S[mi][ni][r]);
            }
        }

        // O += P V
        bf16x8 Pf[2][2];
#pragma unroll
        for (int mi = 0; mi < 2; mi++) {
#pragma unroll
            for (int kk = 0; kk < 2; kk++)
                Pf[mi][kk] = *(const bf16x8*)&Pl[w * 2048 + (mi * 16 + l16) * 64 + kk * 32 + quad * 8];
        }
#pragma unroll
        for (int ni = 0; ni < 8; ni++) {
#pragma unroll
            for (int kk = 0; kk < 2; kk++) {
                bf16x8 Vf = *(const bf16x8*)&Vt[(ni * 16 + l16) * 64 + kk * 32 + quad * 8];
#pragma unroll
                for (int mi = 0; mi < 2; mi++)
                    Oacc[mi][ni] = MFMA_16x16x32_BF16(Pf[mi][kk], Vf, Oacc[mi][ni]);
            }
        }
    }

    // epilogue: normalize by l, write bf16 to [B,T,H*Dh]
    const int b = bh >> 4, h = bh & 15;
#pragma unroll
    for (int mi = 0; mi < 2; mi++) {
#pragma unroll
        for (int r = 0; r < 4; r++) {
            int t = q0 + w * 32 + mi * 16 + quad * 4 + r;
            float inv = 1.0f / lrow[mi][r];
            size_t rowb = ((size_t)(b * 2048 + t)) * 2048 + (size_t)(h * 128);
#pragma unroll
            for (int ni = 0; ni < 8; ni++)
                O[rowb + ni * 16 + l16] = f2b(Oacc[mi][ni][r] * inv);
        }
    }
}

// ---------------------------------------------------------------------------
extern "C" void kernel_launch(void* const* d_in, const int* in_sizes, int n_in,
                              void* d_out, int out_size, void* d_ws, size_t ws_size,
                              hipStream_t stream) {
    const float* x  = (const float*)d_in[0];
    const float* wq = (const float*)d_in[1];
    const float* wp = (const float*)d_in[2];

    char* ws = (char*)d_ws;
    // workspace layout (bytes)
    u16* xb   = (u16*)(ws + 0);            // 16,777,216
    u16* wqb  = (u16*)(ws + 16777216);     // 25,165,824
    u16* wpb  = (u16*)(ws + 41943040);     //  8,388,608
    u16* qkvb = (u16*)(ws + 50331648);     // 50,331,648
    u16* Qr   = (u16*)(ws + 100663296);    // 16,777,216
    u16* Kr   = (u16*)(ws + 117440512);    // 16,777,216
    u16* Vr   = (u16*)(ws + 134217728);    // 16,777,216
    u16* Ob   = (u16*)(ws + 50331648);     // overlays qkvb (free after rope)
    if (ws_size < 150994944) return;       // fail visibly rather than corrupt

    cast3<<<2048, 256, 0, stream>>>(x, wq, wp, xb, wqb, wpb);
    // qkv = x @ w_qkv^T : [4096,6144]
    gemm_bt<1><<<dim3(48, 32), 256, 0, stream>>>(xb, wqb, qkvb, 4096, 6144, 2048);
    rope_split<<<4096, 256, 0, stream>>>(qkvb, Qr, Kr, Vr);
    attn<<<dim3(16, 32), 256, 0, stream>>>(Qr, Kr, Vr, Ob);
    // out = attn_out @ w_proj^T : [4096,2048] fp32
    gemm_bt<0><<<dim3(16, 32), 256, 0, stream>>>(Ob, wpb, (float*)d_out, 4096, 2048, 2048);
}

// Round 2
// 474.723 us; speedup vs baseline: 1.4001x; 1.4001x over previous
//
#include <hip/hip_runtime.h>
#include <stdint.h>

typedef unsigned short u16;
typedef unsigned int   u32;
typedef __attribute__((ext_vector_type(8))) __bf16 bf16x8;
typedef __attribute__((ext_vector_type(4))) float  f32x4;

#define MFMA_16x16x32_BF16(a, b, c) __builtin_amdgcn_mfma_f32_16x16x32_bf16((a), (b), (c), 0, 0, 0)

__device__ __forceinline__ u16 f2b(float f) {
    u32 u = __builtin_bit_cast(u32, f);
    u32 r = (u + 0x7FFFu + ((u >> 16) & 1u)) >> 16;
    return (u16)r;
}
__device__ __forceinline__ float b2f(u16 h) {
    u32 u = ((u32)h) << 16;
    return __builtin_bit_cast(float, u);
}

// async 16B/lane global->LDS. LDS dest is wave-uniform base + lane*16.
__device__ __forceinline__ void gload_lds16(const void* g, void* l) {
    __builtin_amdgcn_global_load_lds(
        (const __attribute__((address_space(1))) u32*)g,
        (__attribute__((address_space(3))) u32*)l,
        16, 0, 0);
}

// ---------------------------------------------------------------------------
// cast fp32 -> bf16 for x (8388608), w_qkv (12582912), w_proj (4194304)
// ---------------------------------------------------------------------------
__global__ __launch_bounds__(256) void cast3(const float* __restrict__ x,
                                             const float* __restrict__ wq,
                                             const float* __restrict__ wp,
                                             u16* __restrict__ xb,
                                             u16* __restrict__ wqb,
                                             u16* __restrict__ wpb) {
    const int n1 = 8388608, n2 = 12582912, n3 = 4194304;
    const int total4 = (n1 + n2 + n3) / 4;
    for (int i = blockIdx.x * blockDim.x + threadIdx.x; i < total4;
         i += gridDim.x * blockDim.x) {
        int e = i * 4;
        const float* src; u16* dst; int off;
        if (e < n1)            { src = x;  dst = xb;  off = e; }
        else if (e < n1 + n2)  { src = wq; dst = wqb; off = e - n1; }
        else                   { src = wp; dst = wpb; off = e - n1 - n2; }
        float4 v = *(const float4*)(src + off);
        ushort4 o;
        o.x = f2b(v.x); o.y = f2b(v.y); o.z = f2b(v.z); o.w = f2b(v.w);
        *(ushort4*)(dst + off) = o;
    }
}

// ---------------------------------------------------------------------------
// C[M,N] = A[M,K] * Bt[N,K]^T  (bf16 in, fp32 accumulate).
// 128x128 tile, BK=64, 256 threads (4 waves, 64x64 each, 4x4 16x16x32 frags).
// ---------------------------------------------------------------------------
template <int OUT_BF16>
__global__ __launch_bounds__(256) void gemm_bt(const u16* __restrict__ A,
                                               const u16* __restrict__ Bt,
                                               void* __restrict__ Cout,
                                               int M, int N, int K) {
    __shared__ u16 Al[128 * 64];
    __shared__ u16 Bl[128 * 64];
    const int tid  = threadIdx.x;
    const int w    = tid >> 6;
    const int lane = tid & 63;
    const int quad = lane >> 4;
    const int l16  = lane & 15;
    const int m0 = blockIdx.y * 128;
    const int n0 = blockIdx.x * 128;
    const int wm = (w >> 1) * 64;
    const int wn = (w & 1) * 64;

    f32x4 acc[4][4];
#pragma unroll
    for (int i = 0; i < 4; i++) {
#pragma unroll
        for (int j = 0; j < 4; j++) acc[i][j] = (f32x4){0.f, 0.f, 0.f, 0.f};
    }

    const u16* Abase = A + (size_t)(m0 + (tid >> 3)) * K + (tid & 7) * 8;
    const u16* Bbase = Bt + (size_t)(n0 + (tid >> 3)) * K + (tid & 7) * 8;
    char* AlB = (char*)Al + w * 1024;
    char* BlB = (char*)Bl + w * 1024;

    for (int k0 = 0; k0 < K; k0 += 64) {
        __syncthreads();
#pragma unroll
        for (int i = 0; i < 4; i++) {
            gload_lds16(Abase + (size_t)i * 32 * K + k0, AlB + i * 4096);
            gload_lds16(Bbase + (size_t)i * 32 * K + k0, BlB + i * 4096);
        }
        __syncthreads();
#pragma unroll
        for (int ks = 0; ks < 2; ks++) {
            bf16x8 Af[4];
#pragma unroll
            for (int mi = 0; mi < 4; mi++)
                Af[mi] = *(const bf16x8*)&Al[(wm + mi * 16 + l16) * 64 + ks * 32 + quad * 8];
#pragma unroll
            for (int ni = 0; ni < 4; ni++) {
                bf16x8 Bf = *(const bf16x8*)&Bl[(wn + ni * 16 + l16) * 64 + ks * 32 + quad * 8];
#pragma unroll
                for (int mi = 0; mi < 4; mi++)
                    acc[mi][ni] = MFMA_16x16x32_BF16(Af[mi], Bf, acc[mi][ni]);
            }
        }
    }

    const int row0 = m0 + wm + quad * 4;
    const int col0 = n0 + wn + l16;
#pragma unroll
    for (int mi = 0; mi < 4; mi++) {
#pragma unroll
        for (int r = 0; r < 4; r++) {
            size_t rowb = (size_t)(row0 + mi * 16 + r) * N;
#pragma unroll
            for (int ni = 0; ni < 4; ni++) {
                float v = acc[mi][ni][r];
                if (OUT_BF16) ((u16*)Cout)[rowb + col0 + ni * 16] = f2b(v);
                else          ((float*)Cout)[rowb + col0 + ni * 16] = v;
            }
        }
    }
}

// ---------------------------------------------------------------------------
// RoPE(q,k): qkv[B,T,3,H,Dh] -> Q,K (roped) in [B,H,T,Dh]. block per (b,t).
// ---------------------------------------------------------------------------
__global__ __launch_bounds__(256) void rope_qk(const u16* __restrict__ qkv,
                                               u16* __restrict__ Q,
                                               u16* __restrict__ K) {
    const int bt = blockIdx.x;          // 0..4095
    const int b = bt >> 11, t = bt & 2047;
    const u16* row = qkv + (size_t)bt * 6144;
    const int tid = threadIdx.x;

#pragma unroll
    for (int it = 0; it < 8; it++) {
        int p   = it * 256 + tid;
        int qk  = p >> 10;          // 0=q, 1=k (uniform per it)
        int rem = p & 1023;
        int h   = rem >> 6;
        int i   = rem & 63;
        float x1 = b2f(row[qk * 2048 + h * 128 + i]);
        float x2 = b2f(row[qk * 2048 + h * 128 + i + 64]);
        float inv = expf(-0.14391156f * (float)i);   // 10000^(-i/64)
        float th  = (float)t * inv;
        float s, c;
        sincosf(th, &s, &c);
        float o1 = x1 * c - x2 * s;
        float o2 = x2 * c + x1 * s;
        u16* dst = (qk ? K : Q) + ((size_t)((b * 16 + h) * 2048 + t)) * 128;
        dst[i]      = f2b(o1);
        dst[i + 64] = f2b(o2);
    }
}

// ---------------------------------------------------------------------------
// V transpose: qkv[B,T,3,H,Dh] (v slice) -> VT[B,H,Dh,T]. grid (32 tc, 32 bh).
// LDS-staged so both global read and write are 16B-vectorized.
// ---------------------------------------------------------------------------
__global__ __launch_bounds__(256) void vtrans(const u16* __restrict__ qkv,
                                              u16* __restrict__ VT) {
    __shared__ u16 S[64 * 136];         // [t][d], stride 136 (16B-aligned, pad)
    const int tc = blockIdx.x;          // t-chunk of 64
    const int bh = blockIdx.y;          // b*16+h
    const int b = bh >> 4, h = bh & 15;
    const int tid = threadIdx.x;

#pragma unroll
    for (int i = 0; i < 4; i++) {
        int idx = i * 256 + tid;
        int t  = idx >> 4;              // 0..63
        int d8 = (idx & 15) * 8;        // 0..120
        uint4 v = *(const uint4*)(qkv + ((size_t)(b * 2048 + tc * 64 + t)) * 6144
                                      + 4096 + h * 128 + d8);
        *(uint4*)&S[t * 136 + d8] = v;
    }
    __syncthreads();
#pragma unroll
    for (int i = 0; i < 4; i++) {
        int idx = i * 256 + tid;
        int d  = idx >> 3;              // 0..127
        int t8 = (idx & 7) * 8;         // 0..56
        u16 tmp[8];
#pragma unroll
        for (int j = 0; j < 8; j++) tmp[j] = S[(t8 + j) * 136 + d];
        *(uint4*)(VT + ((size_t)(bh * 128 + d)) * 2048 + tc * 64 + t8) = *(uint4*)tmp;
    }
}

// ---------------------------------------------------------------------------
// causal flash attention, load-balanced: grid (16 pairs, 32 bh), 256 threads.
// Each block does q-tiles {pair, 31-pair} (64 rows each) => constant 33 k-tiles.
// Each wave owns 16 q-rows. K [64][128] and VT [128][64] staged async.
// ---------------------------------------------------------------------------
__global__ __launch_bounds__(256) void attn(const u16* __restrict__ Q,
                                            const u16* __restrict__ Kg,
                                            const u16* __restrict__ VTg,
                                            u16* __restrict__ O) {
    __shared__ u16 Kl[64 * 128];        // [key][d]
    __shared__ u16 Vt[128 * 64];        // [d][key]
    __shared__ u16 Pl[4 * 16 * 68];     // per-wave P, padded stride 68

    const int tid  = threadIdx.x;
    const int w    = tid >> 6;
    const int lane = tid & 63;
    const int quad = lane >> 4;
    const int l16  = lane & 15;
    const int pair = blockIdx.x;        // 0..15
    const int bh   = blockIdx.y;        // 0..31
    const int b = bh >> 4, h = bh & 15;
    const size_t base = (size_t)bh * 2048 * 128;
    const u16* Qb  = Q + base;
    const u16* Kb  = Kg + base;
    const u16* VTb = VTg + base;        // [128 d][2048 t]
    u16* Plw = Pl + w * 16 * 68;
    const float scale = 0.08838834764831845f;   // 1/sqrt(128)

    for (int s = 0; s < 2; s++) {
        const int qt   = s ? (31 - pair) : pair;
        const int q0   = qt * 64;
        const int row0 = q0 + w * 16;   // this wave's first q-row

        // Q fragments (A-operand: m=l16, k=quad*8+j)
        bf16x8 Qf[4];
#pragma unroll
        for (int kk = 0; kk < 4; kk++)
            Qf[kk] = *(const bf16x8*)&Qb[(size_t)(row0 + l16) * 128 + kk * 32 + quad * 8];

        f32x4 Oacc[8];
#pragma unroll
        for (int ni = 0; ni < 8; ni++) Oacc[ni] = (f32x4){0.f, 0.f, 0.f, 0.f};
        float mrow[4], lrow[4];
#pragma unroll
        for (int r = 0; r < 4; r++) { mrow[r] = -INFINITY; lrow[r] = 0.f; }

        const int nkt = qt + 1;
        for (int kt = 0; kt < nkt; kt++) {
            const int kt0 = kt * 64;
            __syncthreads();
            // stage K tile [64][128]: 4 rows per wave-issue
            {
                const u16* ksrc = Kb + (size_t)(kt0 + (tid >> 4)) * 128 + (tid & 15) * 8;
                char* kdst = (char*)Kl + w * 1024;
#pragma unroll
                for (int i = 0; i < 4; i++)
                    gload_lds16(ksrc + (size_t)i * 16 * 128, kdst + i * 4096);
            }
            // stage VT tile [128][64]: 8 rows per wave-issue
            {
                const u16* vsrc = VTb + (size_t)(w * 8 + (lane >> 3)) * 2048 + kt0 + (lane & 7) * 8;
                char* vdst = (char*)Vt + w * 1024;
#pragma unroll
                for (int i = 0; i < 4; i++)
                    gload_lds16(vsrc + (size_t)i * 32 * 2048, vdst + i * 4096);
            }
            __syncthreads();

            // S = Q K^T  (rows quad*4+r, cols l16 within 16-col groups)
            f32x4 S4[4];
#pragma unroll
            for (int ni = 0; ni < 4; ni++) {
                S4[ni] = (f32x4){0.f, 0.f, 0.f, 0.f};
#pragma unroll
                for (int kk = 0; kk < 4; kk++) {
                    bf16x8 Kf = *(const bf16x8*)&Kl[(ni * 16 + l16) * 128 + kk * 32 + quad * 8];
                    S4[ni] = MFMA_16x16x32_BF16(Qf[kk], Kf, S4[ni]);
                }
            }

            // scale (+ causal mask only on diagonal-straddling tiles)
            const bool needs_mask = (kt0 + 63) > row0;
            float tmax[4] = {-1e30f, -1e30f, -1e30f, -1e30f};
#pragma unroll
            for (int ni = 0; ni < 4; ni++) {
                int kg = kt0 + ni * 16 + l16;
#pragma unroll
                for (int r = 0; r < 4; r++) {
                    float sv = S4[ni][r] * scale;
                    if (needs_mask) {
                        int qg = row0 + quad * 4 + r;
                        sv = (kg > qg) ? -1e30f : sv;
                    }
                    S4[ni][r] = sv;
                    tmax[r] = fmaxf(tmax[r], sv);
                }
            }
#pragma unroll
            for (int r = 0; r < 4; r++) {
#pragma unroll
                for (int off = 1; off < 16; off <<= 1)
                    tmax[r] = fmaxf(tmax[r], __shfl_xor(tmax[r], off));
            }
            float alpha[4];
#pragma unroll
            for (int r = 0; r < 4; r++) {
                float mnew = fmaxf(mrow[r], tmax[r]);
                alpha[r] = __expf(mrow[r] - mnew);
                mrow[r] = mnew;
            }
            float tsum[4] = {0.f, 0.f, 0.f, 0.f};
#pragma unroll
            for (int ni = 0; ni < 4; ni++) {
#pragma unroll
                for (int r = 0; r < 4; r++) {
                    float p = __expf(S4[ni][r] - mrow[r]);
                    S4[ni][r] = p;
                    tsum[r] += p;
                }
            }
#pragma unroll
            for (int r = 0; r < 4; r++) {
#pragma unroll
                for (int off = 1; off < 16; off <<= 1)
                    tsum[r] += __shfl_xor(tsum[r], off);
                lrow[r] = lrow[r] * alpha[r] + tsum[r];
            }
#pragma unroll
            for (int ni = 0; ni < 8; ni++) {
#pragma unroll
                for (int r = 0; r < 4; r++) Oacc[ni][r] *= alpha[r];
            }
            // P -> LDS (C/D layout -> A-operand layout), padded stride 68
#pragma unroll
            for (int ni = 0; ni < 4; ni++) {
#pragma unroll
                for (int r = 0; r < 4; r++)
                    Plw[(quad * 4 + r) * 68 + ni * 16 + l16] = f2b(S4[ni][r]);
            }

            // O += P V
            bf16x8 Pf[2];
#pragma unroll
            for (int kk = 0; kk < 2; kk++)
                Pf[kk] = *(const bf16x8*)&Plw[l16 * 68 + kk * 32 + quad * 8];
#pragma unroll
            for (int ni = 0; ni < 8; ni++) {
#pragma unroll
                for (int kk = 0; kk < 2; kk++) {
                    bf16x8 Vf = *(const bf16x8*)&Vt[(ni * 16 + l16) * 64 + kk * 32 + quad * 8];
                    Oacc[ni] = MFMA_16x16x32_BF16(Pf[kk], Vf, Oacc[ni]);
                }
            }
        }

        // epilogue: O[b, t, h*128 + d] bf16
#pragma unroll
        for (int r = 0; r < 4; r++) {
            int t = row0 + quad * 4 + r;
            float inv = 1.0f / lrow[r];
            size_t rowb = ((size_t)(b * 2048 + t)) * 2048 + (size_t)(h * 128);
#pragma unroll
            for (int ni = 0; ni < 8; ni++)
                O[rowb + ni * 16 + l16] = f2b(Oacc[ni][r] * inv);
        }
    }
}

// ---------------------------------------------------------------------------
extern "C" void kernel_launch(void* const* d_in, const int* in_sizes, int n_in,
                              void* d_out, int out_size, void* d_ws, size_t ws_size,
                              hipStream_t stream) {
    const float* x  = (const float*)d_in[0];
    const float* wq = (const float*)d_in[1];
    const float* wp = (const float*)d_in[2];

    char* ws = (char*)d_ws;
    u16* xb   = (u16*)(ws + 0);            // 16,777,216
    u16* wqb  = (u16*)(ws + 16777216);     // 25,165,824
    u16* wpb  = (u16*)(ws + 41943040);     //  8,388,608
    u16* qkvb = (u16*)(ws + 50331648);     // 50,331,648
    u16* Qr   = (u16*)(ws + 100663296);    // 16,777,216
    u16* Kr   = (u16*)(ws + 117440512);    // 16,777,216
    u16* VTt  = (u16*)(ws + 134217728);    // 16,777,216 (V^T, [B,H,Dh,T])
    u16* Ob   = (u16*)(ws + 50331648);     // overlays qkvb (free after rope/vtrans)
    if (ws_size < 150994944) return;

    cast3<<<2048, 256, 0, stream>>>(x, wq, wp, xb, wqb, wpb);
    gemm_bt<1><<<dim3(48, 32), 256, 0, stream>>>(xb, wqb, qkvb, 4096, 6144, 2048);
    rope_qk<<<4096, 256, 0, stream>>>(qkvb, Qr, Kr);
    vtrans<<<dim3(32, 32), 256, 0, stream>>>(qkvb, VTt);
    attn<<<dim3(16, 32), 256, 0, stream>>>(Qr, Kr, VTt, Ob);
    gemm_bt<0><<<dim3(16, 32), 256, 0, stream>>>(Ob, wpb, (float*)d_out, 4096, 2048, 2048);
}

// Round 3
// 458.866 us; speedup vs baseline: 1.4485x; 1.0346x over previous
//
#include <hip/hip_runtime.h>
#include <stdint.h>

typedef unsigned short u16;
typedef unsigned int   u32;
typedef __attribute__((ext_vector_type(8))) __bf16 bf16x8;
typedef __attribute__((ext_vector_type(4))) float  f32x4;

#define MFMA_16x16x32_BF16(a, b, c) __builtin_amdgcn_mfma_f32_16x16x32_bf16((a), (b), (c), 0, 0, 0)

__device__ __forceinline__ u16 f2b(float f) {
    u32 u = __builtin_bit_cast(u32, f);
    u32 r = (u + 0x7FFFu + ((u >> 16) & 1u)) >> 16;
    return (u16)r;
}
__device__ __forceinline__ float b2f(u16 h) {
    u32 u = ((u32)h) << 16;
    return __builtin_bit_cast(float, u);
}

// async 16B/lane global->LDS. LDS dest is wave-uniform base + lane*16.
__device__ __forceinline__ void gload_lds16(const void* g, void* l) {
    __builtin_amdgcn_global_load_lds(
        (const __attribute__((address_space(1))) u32*)g,
        (__attribute__((address_space(3))) u32*)l,
        16, 0, 0);
}

// ---------------------------------------------------------------------------
// cast fp32 -> bf16 for x (8388608), w_qkv (12582912), w_proj (4194304)
// ---------------------------------------------------------------------------
__global__ __launch_bounds__(256) void cast3(const float* __restrict__ x,
                                             const float* __restrict__ wq,
                                             const float* __restrict__ wp,
                                             u16* __restrict__ xb,
                                             u16* __restrict__ wqb,
                                             u16* __restrict__ wpb) {
    const int n1 = 8388608, n2 = 12582912, n3 = 4194304;
    const int total4 = (n1 + n2 + n3) / 4;
    for (int i = blockIdx.x * blockDim.x + threadIdx.x; i < total4;
         i += gridDim.x * blockDim.x) {
        int e = i * 4;
        const float* src; u16* dst; int off;
        if (e < n1)            { src = x;  dst = xb;  off = e; }
        else if (e < n1 + n2)  { src = wq; dst = wqb; off = e - n1; }
        else                   { src = wp; dst = wpb; off = e - n1 - n2; }
        float4 v = *(const float4*)(src + off);
        ushort4 o;
        o.x = f2b(v.x); o.y = f2b(v.y); o.z = f2b(v.z); o.w = f2b(v.w);
        *(ushort4*)(dst + off) = o;
    }
}

// ---------------------------------------------------------------------------
// C[M,N] = A[M,K] * Bt[N,K]^T  (bf16 in, fp32 accumulate).
// 128x128 tile, BK=64, 256 threads (4 waves, 64x64 each, 4x4 16x16x32 frags).
// ---------------------------------------------------------------------------
template <int OUT_BF16>
__global__ __launch_bounds__(256) void gemm_bt(const u16* __restrict__ A,
                                               const u16* __restrict__ Bt,
                                               void* __restrict__ Cout,
                                               int M, int N, int K) {
    __shared__ u16 Al[128 * 64];
    __shared__ u16 Bl[128 * 64];
    const int tid  = threadIdx.x;
    const int w    = tid >> 6;
    const int lane = tid & 63;
    const int quad = lane >> 4;
    const int l16  = lane & 15;
    const int m0 = blockIdx.y * 128;
    const int n0 = blockIdx.x * 128;
    const int wm = (w >> 1) * 64;
    const int wn = (w & 1) * 64;

    f32x4 acc[4][4];
#pragma unroll
    for (int i = 0; i < 4; i++) {
#pragma unroll
        for (int j = 0; j < 4; j++) acc[i][j] = (f32x4){0.f, 0.f, 0.f, 0.f};
    }

    const u16* Abase = A + (size_t)(m0 + (tid >> 3)) * K + (tid & 7) * 8;
    const u16* Bbase = Bt + (size_t)(n0 + (tid >> 3)) * K + (tid & 7) * 8;
    char* AlB = (char*)Al + w * 1024;
    char* BlB = (char*)Bl + w * 1024;

    for (int k0 = 0; k0 < K; k0 += 64) {
        __syncthreads();
#pragma unroll
        for (int i = 0; i < 4; i++) {
            gload_lds16(Abase + (size_t)i * 32 * K + k0, AlB + i * 4096);
            gload_lds16(Bbase + (size_t)i * 32 * K + k0, BlB + i * 4096);
        }
        __syncthreads();
#pragma unroll
        for (int ks = 0; ks < 2; ks++) {
            bf16x8 Af[4];
#pragma unroll
            for (int mi = 0; mi < 4; mi++)
                Af[mi] = *(const bf16x8*)&Al[(wm + mi * 16 + l16) * 64 + ks * 32 + quad * 8];
#pragma unroll
            for (int ni = 0; ni < 4; ni++) {
                bf16x8 Bf = *(const bf16x8*)&Bl[(wn + ni * 16 + l16) * 64 + ks * 32 + quad * 8];
#pragma unroll
                for (int mi = 0; mi < 4; mi++)
                    acc[mi][ni] = MFMA_16x16x32_BF16(Af[mi], Bf, acc[mi][ni]);
            }
        }
    }

    const int row0 = m0 + wm + quad * 4;
    const int col0 = n0 + wn + l16;
#pragma unroll
    for (int mi = 0; mi < 4; mi++) {
#pragma unroll
        for (int r = 0; r < 4; r++) {
            size_t rowb = (size_t)(row0 + mi * 16 + r) * N;
#pragma unroll
            for (int ni = 0; ni < 4; ni++) {
                float v = acc[mi][ni][r];
                if (OUT_BF16) ((u16*)Cout)[rowb + col0 + ni * 16] = f2b(v);
                else          ((float*)Cout)[rowb + col0 + ni * 16] = v;
            }
        }
    }
}

// ---------------------------------------------------------------------------
// RoPE(q,k): qkv[B,T,3,H,Dh] -> Q,K (roped) in [B,H,T,Dh]. block per (b,t).
// ---------------------------------------------------------------------------
__global__ __launch_bounds__(256) void rope_qk(const u16* __restrict__ qkv,
                                               u16* __restrict__ Q,
                                               u16* __restrict__ K) {
    const int bt = blockIdx.x;          // 0..4095
    const int b = bt >> 11, t = bt & 2047;
    const u16* row = qkv + (size_t)bt * 6144;
    const int tid = threadIdx.x;

#pragma unroll
    for (int it = 0; it < 8; it++) {
        int p   = it * 256 + tid;
        int qk  = p >> 10;          // 0=q, 1=k (uniform per it)
        int rem = p & 1023;
        int h   = rem >> 6;
        int i   = rem & 63;
        float x1 = b2f(row[qk * 2048 + h * 128 + i]);
        float x2 = b2f(row[qk * 2048 + h * 128 + i + 64]);
        float inv = expf(-0.14391156f * (float)i);   // 10000^(-i/64)
        float th  = (float)t * inv;
        float s, c;
        sincosf(th, &s, &c);
        float o1 = x1 * c - x2 * s;
        float o2 = x2 * c + x1 * s;
        u16* dst = (qk ? K : Q) + ((size_t)((b * 16 + h) * 2048 + t)) * 128;
        dst[i]      = f2b(o1);
        dst[i + 64] = f2b(o2);
    }
}

// ---------------------------------------------------------------------------
// V transpose: qkv[B,T,3,H,Dh] (v slice) -> VT[B,H,Dh,T]. grid (32 tc, 32 bh).
// ---------------------------------------------------------------------------
__global__ __launch_bounds__(256) void vtrans(const u16* __restrict__ qkv,
                                              u16* __restrict__ VT) {
    __shared__ u16 S[64 * 136];         // [t][d], stride 136
    const int tc = blockIdx.x;
    const int bh = blockIdx.y;
    const int b = bh >> 4, h = bh & 15;
    const int tid = threadIdx.x;

#pragma unroll
    for (int i = 0; i < 4; i++) {
        int idx = i * 256 + tid;
        int t  = idx >> 4;
        int d8 = (idx & 15) * 8;
        uint4 v = *(const uint4*)(qkv + ((size_t)(b * 2048 + tc * 64 + t)) * 6144
                                      + 4096 + h * 128 + d8);
        *(uint4*)&S[t * 136 + d8] = v;
    }
    __syncthreads();
#pragma unroll
    for (int i = 0; i < 4; i++) {
        int idx = i * 256 + tid;
        int d  = idx >> 3;
        int t8 = (idx & 7) * 8;
        u16 tmp[8];
#pragma unroll
        for (int j = 0; j < 8; j++) tmp[j] = S[(t8 + j) * 136 + d];
        *(uint4*)(VT + ((size_t)(bh * 128 + d)) * 2048 + tc * 64 + t8) = *(uint4*)tmp;
    }
}

// ---------------------------------------------------------------------------
// causal flash attention v3: S^T trick (softmax in-lane) + double-buffered
// async K/V staging (1 barrier/tile, prefetch hides vmcnt drain).
// grid (16 pairs, 32 bh), 256 thr. Block = 64 q-rows; wave = 16 q-rows.
// ---------------------------------------------------------------------------
__global__ __launch_bounds__(256) void attn(const u16* __restrict__ Q,
                                            const u16* __restrict__ Kg,
                                            const u16* __restrict__ VTg,
                                            u16* __restrict__ O) {
    __shared__ u16 Kl[2][64 * 128];     // [buf][key][d]
    __shared__ u16 Vt[2][128 * 64];     // [buf][d][key]
    __shared__ u16 Pl[4 * 16 * 76];     // per-wave P[q][key], stride 76

    const int tid  = threadIdx.x;
    const int w    = tid >> 6;
    const int lane = tid & 63;
    const int quad = lane >> 4;
    const int l16  = lane & 15;
    const int pair = blockIdx.x;        // 0..15
    const int bh   = blockIdx.y;        // 0..31
    const int b = bh >> 4, h = bh & 15;
    const size_t base = (size_t)bh * 2048 * 128;
    const u16* Qb  = Q + base;
    const u16* Kb  = Kg + base;
    const u16* VTb = VTg + base;        // [128 d][2048 t]
    u16* Plw = Pl + w * 16 * 76;
    const float scale = 0.08838834764831845f;   // 1/sqrt(128)

    // per-wave staging source offsets
    const int krow = tid >> 4, kcol = (tid & 15) * 8;          // K tile
    const int vrow = w * 8 + (lane >> 3), vcol = (lane & 7) * 8; // VT tile

    for (int s = 0; s < 2; s++) {
        const int qt   = s ? (31 - pair) : pair;
        const int q0   = qt * 64;
        const int row0 = q0 + w * 16;

        // Q fragment (used as B operand: B[k=quad*8+j][n=l16] = Q[q=l16][d])
        bf16x8 Qf[4];
#pragma unroll
        for (int kk = 0; kk < 4; kk++)
            Qf[kk] = *(const bf16x8*)&Qb[(size_t)(row0 + l16) * 128 + kk * 32 + quad * 8];

        f32x4 Oacc[8];
#pragma unroll
        for (int ni = 0; ni < 8; ni++) Oacc[ni] = (f32x4){0.f, 0.f, 0.f, 0.f};
        float mrow = -1e30f, lrow = 0.f;    // per-lane: q = row0 + l16

        const int nkt = qt + 1;

        // protect buf0 from previous s-iteration, then stage tile 0
        __syncthreads();
        {
            const u16* ksrc = Kb + (size_t)krow * 128 + kcol;
            char* kdst = (char*)Kl[0] + w * 1024;
            const u16* vsrc = VTb + (size_t)vrow * 2048 + vcol;
            char* vdst = (char*)Vt[0] + w * 1024;
#pragma unroll
            for (int i = 0; i < 4; i++) {
                gload_lds16(ksrc + (size_t)i * 16 * 128, kdst + i * 4096);
                gload_lds16(vsrc + (size_t)i * 32 * 2048, vdst + i * 4096);
            }
        }

        for (int kt = 0; kt < nkt; kt++) {
            const int kt0 = kt * 64;
            const int cur = kt & 1;
            __syncthreads();    // drains this wave's async loads, syncs block

            // prefetch next tile into the other buffer (latency hidden by compute)
            if (kt + 1 < nkt) {
                const int kt1 = kt0 + 64;
                const u16* ksrc = Kb + (size_t)(kt1 + krow) * 128 + kcol;
                char* kdst = (char*)Kl[cur ^ 1] + w * 1024;
                const u16* vsrc = VTb + (size_t)vrow * 2048 + kt1 + vcol;
                char* vdst = (char*)Vt[cur ^ 1] + w * 1024;
#pragma unroll
                for (int i = 0; i < 4; i++) {
                    gload_lds16(ksrc + (size_t)i * 16 * 128, kdst + i * 4096);
                    gload_lds16(vsrc + (size_t)i * 32 * 2048, vdst + i * 4096);
                }
            }

            const u16* Klc = Kl[cur];
            const u16* Vtc = Vt[cur];

            // S^T = K Q^T : D[key][q], q = l16, key = mi*16 + quad*4 + r
            f32x4 ST[4];
#pragma unroll
            for (int mi = 0; mi < 4; mi++) ST[mi] = (f32x4){0.f, 0.f, 0.f, 0.f};
#pragma unroll
            for (int kk = 0; kk < 4; kk++) {
#pragma unroll
                for (int mi = 0; mi < 4; mi++) {
                    bf16x8 Kf = *(const bf16x8*)&Klc[(mi * 16 + l16) * 128 + kk * 32 + quad * 8];
                    ST[mi] = MFMA_16x16x32_BF16(Kf, Qf[kk], ST[mi]);
                }
            }

            // scale + mask (diagonal tiles only); all softmax state per-lane
            const bool needs_mask = (kt0 + 63) > row0;
            const int qg = row0 + l16;
            float tmax = -1e30f;
#pragma unroll
            for (int mi = 0; mi < 4; mi++) {
#pragma unroll
                for (int r = 0; r < 4; r++) {
                    float sv = ST[mi][r] * scale;
                    if (needs_mask) {
                        int kg = kt0 + mi * 16 + quad * 4 + r;
                        sv = (kg > qg) ? -1e30f : sv;
                    }
                    ST[mi][r] = sv;
                    tmax = fmaxf(tmax, sv);
                }
            }
            // cross-quad max (row max over all 64 keys)
            tmax = fmaxf(tmax, __shfl_xor(tmax, 16));
            tmax = fmaxf(tmax, __shfl_xor(tmax, 32));

            float mnew  = fmaxf(mrow, tmax);
            float alpha = __expf(mrow - mnew);
            mrow = mnew;

            float tsum = 0.f;
#pragma unroll
            for (int mi = 0; mi < 4; mi++) {
#pragma unroll
                for (int r = 0; r < 4; r++) {
                    float p = __expf(ST[mi][r] - mnew);
                    ST[mi][r] = p;
                    tsum += p;
                }
            }
            lrow = lrow * alpha + tsum;     // per-lane partial (this lane's keys)

            // P[q][key] -> LDS: pack r=0..3 (consecutive keys) into one b64
#pragma unroll
            for (int mi = 0; mi < 4; mi++) {
                ushort4 pk;
                pk.x = f2b(ST[mi][0]); pk.y = f2b(ST[mi][1]);
                pk.z = f2b(ST[mi][2]); pk.w = f2b(ST[mi][3]);
                *(ushort4*)&Plw[l16 * 76 + mi * 16 + quad * 4] = pk;
            }

            // alpha broadcast to C-layout rows (row = quad*4 + r <-> q)
            float aRow[4];
#pragma unroll
            for (int r = 0; r < 4; r++) aRow[r] = __shfl(alpha, quad * 4 + r);
#pragma unroll
            for (int ni = 0; ni < 8; ni++) {
#pragma unroll
                for (int r = 0; r < 4; r++) Oacc[ni][r] *= aRow[r];
            }

            // O += P V   (P as A operand: A[m=l16 q][k=quad*8+j key])
            bf16x8 Pf[2];
#pragma unroll
            for (int kk = 0; kk < 2; kk++)
                Pf[kk] = *(const bf16x8*)&Plw[l16 * 76 + kk * 32 + quad * 8];
#pragma unroll
            for (int kk = 0; kk < 2; kk++) {
#pragma unroll
                for (int ni = 0; ni < 8; ni++) {
                    bf16x8 Vf = *(const bf16x8*)&Vtc[(ni * 16 + l16) * 64 + kk * 32 + quad * 8];
                    Oacc[ni] = MFMA_16x16x32_BF16(Pf[kk], Vf, Oacc[ni]);
                }
            }
        }

        // final l: reduce per-lane partials across quads, broadcast to rows
        lrow += __shfl_xor(lrow, 16);
        lrow += __shfl_xor(lrow, 32);
        float inv = 1.0f / lrow;
        float iRow[4];
#pragma unroll
        for (int r = 0; r < 4; r++) iRow[r] = __shfl(inv, quad * 4 + r);

#pragma unroll
        for (int r = 0; r < 4; r++) {
            int t = row0 + quad * 4 + r;
            size_t rowb = ((size_t)(b * 2048 + t)) * 2048 + (size_t)(h * 128);
#pragma unroll
            for (int ni = 0; ni < 8; ni++)
                O[rowb + ni * 16 + l16] = f2b(Oacc[ni][r] * iRow[r]);
        }
    }
}

// ---------------------------------------------------------------------------
extern "C" void kernel_launch(void* const* d_in, const int* in_sizes, int n_in,
                              void* d_out, int out_size, void* d_ws, size_t ws_size,
                              hipStream_t stream) {
    const float* x  = (const float*)d_in[0];
    const float* wq = (const float*)d_in[1];
    const float* wp = (const float*)d_in[2];

    char* ws = (char*)d_ws;
    u16* xb   = (u16*)(ws + 0);            // 16,777,216
    u16* wqb  = (u16*)(ws + 16777216);     // 25,165,824
    u16* wpb  = (u16*)(ws + 41943040);     //  8,388,608
    u16* qkvb = (u16*)(ws + 50331648);     // 50,331,648
    u16* Qr   = (u16*)(ws + 100663296);    // 16,777,216
    u16* Kr   = (u16*)(ws + 117440512);    // 16,777,216
    u16* VTt  = (u16*)(ws + 134217728);    // 16,777,216 (V^T, [B,H,Dh,T])
    u16* Ob   = (u16*)(ws + 50331648);     // overlays qkvb (free after rope/vtrans)
    if (ws_size < 150994944) return;

    cast3<<<2048, 256, 0, stream>>>(x, wq, wp, xb, wqb, wpb);
    gemm_bt<1><<<dim3(48, 32), 256, 0, stream>>>(xb, wqb, qkvb, 4096, 6144, 2048);
    rope_qk<<<4096, 256, 0, stream>>>(qkvb, Qr, Kr);
    vtrans<<<dim3(32, 32), 256, 0, stream>>>(qkvb, VTt);
    attn<<<dim3(16, 32), 256, 0, stream>>>(Qr, Kr, VTt, Ob);
    gemm_bt<0><<<dim3(16, 32), 256, 0, stream>>>(Ob, wpb, (float*)d_out, 4096, 2048, 2048);
}

// Round 4
// 405.289 us; speedup vs baseline: 1.6399x; 1.1322x over previous
//
#include <hip/hip_runtime.h>
#include <stdint.h>

typedef unsigned short u16;
typedef unsigned int   u32;
typedef __attribute__((ext_vector_type(8))) __bf16 bf16x8;
typedef __attribute__((ext_vector_type(4))) float  f32x4;

#define MFMA_16x16x32_BF16(a, b, c) __builtin_amdgcn_mfma_f32_16x16x32_bf16((a), (b), (c), 0, 0, 0)

__device__ __forceinline__ u16 f2b(float f) {
    u32 u = __builtin_bit_cast(u32, f);
    u32 r = (u + 0x7FFFu + ((u >> 16) & 1u)) >> 16;
    return (u16)r;
}
__device__ __forceinline__ float b2f(u16 h) {
    u32 u = ((u32)h) << 16;
    return __builtin_bit_cast(float, u);
}

// async 16B/lane global->LDS. LDS dest is wave-uniform base + lane*16.
__device__ __forceinline__ void gload_lds16(const void* g, void* l) {
    __builtin_amdgcn_global_load_lds(
        (const __attribute__((address_space(1))) u32*)g,
        (__attribute__((address_space(3))) u32*)l,
        16, 0, 0);
}

// ---------------------------------------------------------------------------
// cast fp32 -> bf16 for x (8388608), w_qkv (12582912), w_proj (4194304)
// ---------------------------------------------------------------------------
__global__ __launch_bounds__(256) void cast3(const float* __restrict__ x,
                                             const float* __restrict__ wq,
                                             const float* __restrict__ wp,
                                             u16* __restrict__ xb,
                                             u16* __restrict__ wqb,
                                             u16* __restrict__ wpb) {
    const int n1 = 8388608, n2 = 12582912, n3 = 4194304;
    const int total4 = (n1 + n2 + n3) / 4;
    for (int i = blockIdx.x * blockDim.x + threadIdx.x; i < total4;
         i += gridDim.x * blockDim.x) {
        int e = i * 4;
        const float* src; u16* dst; int off;
        if (e < n1)            { src = x;  dst = xb;  off = e; }
        else if (e < n1 + n2)  { src = wq; dst = wqb; off = e - n1; }
        else                   { src = wp; dst = wpb; off = e - n1 - n2; }
        float4 v = *(const float4*)(src + off);
        ushort4 o;
        o.x = f2b(v.x); o.y = f2b(v.y); o.z = f2b(v.z); o.w = f2b(v.w);
        *(ushort4*)(dst + off) = o;
    }
}

// ---------------------------------------------------------------------------
// C[M,N] = A[M,K] * Bt[N,K]^T  (bf16 in, fp32 accumulate).
// 128x128 tile, BK=64, 256 threads. LDS tiles XOR-swizzled:
// 16B block (row, c) lives at LDS position (row, c ^ (row&7)) -> fragment
// ds_read_b128 spreads l16 over all 8 bank groups (2-way residual, free).
// ---------------------------------------------------------------------------
template <int OUT_BF16>
__global__ __launch_bounds__(256) void gemm_bt(const u16* __restrict__ A,
                                               const u16* __restrict__ Bt,
                                               void* __restrict__ Cout,
                                               int M, int N, int K) {
    __shared__ u16 Al[128 * 64];
    __shared__ u16 Bl[128 * 64];
    const int tid  = threadIdx.x;
    const int w    = tid >> 6;
    const int lane = tid & 63;
    const int quad = lane >> 4;
    const int l16  = lane & 15;
    const int m0 = blockIdx.y * 128;
    const int n0 = blockIdx.x * 128;
    const int wm = (w >> 1) * 64;
    const int wn = (w & 1) * 64;

    f32x4 acc[4][4];
#pragma unroll
    for (int i = 0; i < 4; i++) {
#pragma unroll
        for (int j = 0; j < 4; j++) acc[i][j] = (f32x4){0.f, 0.f, 0.f, 0.f};
    }

    // staging: row = tid>>3 (+32/issue), col block (tid&7) ^ (row&7)
    const int srow = tid >> 3;
    const int scol = ((tid & 7) ^ (srow & 7)) * 8;
    const u16* Abase = A + (size_t)(m0 + srow) * K + scol;
    const u16* Bbase = Bt + (size_t)(n0 + srow) * K + scol;
    char* AlB = (char*)Al + w * 1024;
    char* BlB = (char*)Bl + w * 1024;
    const int fx = (l16 & 7);           // fragment-read swizzle (row&7 = l16&7)

    for (int k0 = 0; k0 < K; k0 += 64) {
        __syncthreads();
#pragma unroll
        for (int i = 0; i < 4; i++) {
            gload_lds16(Abase + (size_t)i * 32 * K + k0, AlB + i * 4096);
            gload_lds16(Bbase + (size_t)i * 32 * K + k0, BlB + i * 4096);
        }
        __syncthreads();
#pragma unroll
        for (int ks = 0; ks < 2; ks++) {
            const int cb = ((ks * 4 + quad) ^ fx) * 8;
            bf16x8 Af[4];
#pragma unroll
            for (int mi = 0; mi < 4; mi++)
                Af[mi] = *(const bf16x8*)&Al[(wm + mi * 16 + l16) * 64 + cb];
#pragma unroll
            for (int ni = 0; ni < 4; ni++) {
                bf16x8 Bf = *(const bf16x8*)&Bl[(wn + ni * 16 + l16) * 64 + cb];
#pragma unroll
                for (int mi = 0; mi < 4; mi++)
                    acc[mi][ni] = MFMA_16x16x32_BF16(Af[mi], Bf, acc[mi][ni]);
            }
        }
    }

    const int row0 = m0 + wm + quad * 4;
    const int col0 = n0 + wn + l16;
#pragma unroll
    for (int mi = 0; mi < 4; mi++) {
#pragma unroll
        for (int r = 0; r < 4; r++) {
            size_t rowb = (size_t)(row0 + mi * 16 + r) * N;
#pragma unroll
            for (int ni = 0; ni < 4; ni++) {
                float v = acc[mi][ni][r];
                if (OUT_BF16) ((u16*)Cout)[rowb + col0 + ni * 16] = f2b(v);
                else          ((float*)Cout)[rowb + col0 + ni * 16] = v;
            }
        }
    }
}

// ---------------------------------------------------------------------------
// RoPE(q,k): qkv[B,T,3,H,Dh] -> Q,K (roped) in [B,H,T,Dh]. block per (b,t).
// ---------------------------------------------------------------------------
__global__ __launch_bounds__(256) void rope_qk(const u16* __restrict__ qkv,
                                               u16* __restrict__ Q,
                                               u16* __restrict__ K) {
    const int bt = blockIdx.x;          // 0..4095
    const int b = bt >> 11, t = bt & 2047;
    const u16* row = qkv + (size_t)bt * 6144;
    const int tid = threadIdx.x;

#pragma unroll
    for (int it = 0; it < 8; it++) {
        int p   = it * 256 + tid;
        int qk  = p >> 10;          // 0=q, 1=k (uniform per it)
        int rem = p & 1023;
        int h   = rem >> 6;
        int i   = rem & 63;
        float x1 = b2f(row[qk * 2048 + h * 128 + i]);
        float x2 = b2f(row[qk * 2048 + h * 128 + i + 64]);
        float inv = expf(-0.14391156f * (float)i);   // 10000^(-i/64)
        float th  = (float)t * inv;
        float s, c;
        sincosf(th, &s, &c);
        float o1 = x1 * c - x2 * s;
        float o2 = x2 * c + x1 * s;
        u16* dst = (qk ? K : Q) + ((size_t)((b * 16 + h) * 2048 + t)) * 128;
        dst[i]      = f2b(o1);
        dst[i + 64] = f2b(o2);
    }
}

// ---------------------------------------------------------------------------
// V transpose: qkv[B,T,3,H,Dh] (v slice) -> VT[B,H,Dh,T]. grid (32 tc, 32 bh).
// ---------------------------------------------------------------------------
__global__ __launch_bounds__(256) void vtrans(const u16* __restrict__ qkv,
                                              u16* __restrict__ VT) {
    __shared__ u16 S[64 * 136];         // [t][d], stride 136
    const int tc = blockIdx.x;
    const int bh = blockIdx.y;
    const int b = bh >> 4, h = bh & 15;
    const int tid = threadIdx.x;

#pragma unroll
    for (int i = 0; i < 4; i++) {
        int idx = i * 256 + tid;
        int t  = idx >> 4;
        int d8 = (idx & 15) * 8;
        uint4 v = *(const uint4*)(qkv + ((size_t)(b * 2048 + tc * 64 + t)) * 6144
                                      + 4096 + h * 128 + d8);
        *(uint4*)&S[t * 136 + d8] = v;
    }
    __syncthreads();
#pragma unroll
    for (int i = 0; i < 4; i++) {
        int idx = i * 256 + tid;
        int d  = idx >> 3;
        int t8 = (idx & 7) * 8;
        u16 tmp[8];
#pragma unroll
        for (int j = 0; j < 8; j++) tmp[j] = S[(t8 + j) * 136 + d];
        *(uint4*)(VT + ((size_t)(bh * 128 + d)) * 2048 + tc * 64 + t8) = *(uint4*)tmp;
    }
}

// ---------------------------------------------------------------------------
// causal flash attention v4: v3 + XOR-swizzled K/V LDS tiles.
// grid (16 pairs, 32 bh), 256 thr. Block = 64 q-rows; wave = 16 q-rows.
// ---------------------------------------------------------------------------
__global__ __launch_bounds__(256) void attn(const u16* __restrict__ Q,
                                            const u16* __restrict__ Kg,
                                            const u16* __restrict__ VTg,
                                            u16* __restrict__ O) {
    __shared__ u16 Kl[2][64 * 128];     // [buf][key][d], swizzled
    __shared__ u16 Vt[2][128 * 64];     // [buf][d][key], swizzled
    __shared__ u16 Pl[4 * 16 * 76];     // per-wave P[q][key], stride 76

    const int tid  = threadIdx.x;
    const int w    = tid >> 6;
    const int lane = tid & 63;
    const int quad = lane >> 4;
    const int l16  = lane & 15;
    const int pair = blockIdx.x;        // 0..15
    const int bh   = blockIdx.y;        // 0..31
    const int b = bh >> 4, h = bh & 15;
    const size_t base = (size_t)bh * 2048 * 128;
    const u16* Qb  = Q + base;
    const u16* Kb  = Kg + base;
    const u16* VTb = VTg + base;        // [128 d][2048 t]
    u16* Plw = Pl + w * 16 * 76;
    const float scale = 0.08838834764831845f;   // 1/sqrt(128)

    // staging offsets with XOR swizzle: LDS pos (row, p) holds global (row, p^(row&7))
    const int krow = tid >> 4;                              // K tile: 16 rows/issue-step
    const int kcol = (((tid & 15) ^ (krow & 7)) * 8);       // u16 units
    const int vrow = w * 8 + (lane >> 3);                   // VT tile: 32 rows/issue-step
    const int vcol = (((lane & 7) ^ (vrow & 7)) * 8);
    const int fx   = (l16 & 7);                             // fragment-read swizzle

    for (int s = 0; s < 2; s++) {
        const int qt   = s ? (31 - pair) : pair;
        const int q0   = qt * 64;
        const int row0 = q0 + w * 16;

        // Q fragment (B operand of S^T MFMA)
        bf16x8 Qf[4];
#pragma unroll
        for (int kk = 0; kk < 4; kk++)
            Qf[kk] = *(const bf16x8*)&Qb[(size_t)(row0 + l16) * 128 + kk * 32 + quad * 8];

        f32x4 Oacc[8];
#pragma unroll
        for (int ni = 0; ni < 8; ni++) Oacc[ni] = (f32x4){0.f, 0.f, 0.f, 0.f};
        float mrow = -1e30f, lrow = 0.f;    // per-lane: q = row0 + l16

        const int nkt = qt + 1;

        __syncthreads();    // protect buf0 from previous s-iteration
        {
            const u16* ksrc = Kb + (size_t)krow * 128 + kcol;
            char* kdst = (char*)Kl[0] + w * 1024;
            const u16* vsrc = VTb + (size_t)vrow * 2048 + vcol;
            char* vdst = (char*)Vt[0] + w * 1024;
#pragma unroll
            for (int i = 0; i < 4; i++) {
                gload_lds16(ksrc + (size_t)i * 16 * 128, kdst + i * 4096);
                gload_lds16(vsrc + (size_t)i * 32 * 2048, vdst + i * 4096);
            }
        }

        for (int kt = 0; kt < nkt; kt++) {
            const int kt0 = kt * 64;
            const int cur = kt & 1;
            __syncthreads();    // drains async loads, syncs block

            // prefetch next tile into the other buffer
            if (kt + 1 < nkt) {
                const int kt1 = kt0 + 64;
                const u16* ksrc = Kb + (size_t)(kt1 + krow) * 128 + kcol;
                char* kdst = (char*)Kl[cur ^ 1] + w * 1024;
                const u16* vsrc = VTb + (size_t)vrow * 2048 + kt1 + vcol;
                char* vdst = (char*)Vt[cur ^ 1] + w * 1024;
#pragma unroll
                for (int i = 0; i < 4; i++) {
                    gload_lds16(ksrc + (size_t)i * 16 * 128, kdst + i * 4096);
                    gload_lds16(vsrc + (size_t)i * 32 * 2048, vdst + i * 4096);
                }
            }

            const u16* Klc = Kl[cur];
            const u16* Vtc = Vt[cur];

            // S^T = K Q^T : D[key][q], q = l16, key = mi*16 + quad*4 + r
            f32x4 ST[4];
#pragma unroll
            for (int mi = 0; mi < 4; mi++) ST[mi] = (f32x4){0.f, 0.f, 0.f, 0.f};
#pragma unroll
            for (int kk = 0; kk < 4; kk++) {
                const int cb = ((kk * 4 + quad) ^ fx) * 8;
#pragma unroll
                for (int mi = 0; mi < 4; mi++) {
                    bf16x8 Kf = *(const bf16x8*)&Klc[(mi * 16 + l16) * 128 + cb];
                    ST[mi] = MFMA_16x16x32_BF16(Kf, Qf[kk], ST[mi]);
                }
            }

            // scale + mask (diagonal tiles only); softmax state per-lane
            const bool needs_mask = (kt0 + 63) > row0;
            const int qg = row0 + l16;
            float tmax = -1e30f;
#pragma unroll
            for (int mi = 0; mi < 4; mi++) {
#pragma unroll
                for (int r = 0; r < 4; r++) {
                    float sv = ST[mi][r] * scale;
                    if (needs_mask) {
                        int kg = kt0 + mi * 16 + quad * 4 + r;
                        sv = (kg > qg) ? -1e30f : sv;
                    }
                    ST[mi][r] = sv;
                    tmax = fmaxf(tmax, sv);
                }
            }
            tmax = fmaxf(tmax, __shfl_xor(tmax, 16));
            tmax = fmaxf(tmax, __shfl_xor(tmax, 32));

            float mnew  = fmaxf(mrow, tmax);
            float alpha = __expf(mrow - mnew);
            mrow = mnew;

            float tsum = 0.f;
#pragma unroll
            for (int mi = 0; mi < 4; mi++) {
#pragma unroll
                for (int r = 0; r < 4; r++) {
                    float p = __expf(ST[mi][r] - mnew);
                    ST[mi][r] = p;
                    tsum += p;
                }
            }
            lrow = lrow * alpha + tsum;

            // P[q][key] -> LDS (b64 packs, padded stride 76)
#pragma unroll
            for (int mi = 0; mi < 4; mi++) {
                ushort4 pk;
                pk.x = f2b(ST[mi][0]); pk.y = f2b(ST[mi][1]);
                pk.z = f2b(ST[mi][2]); pk.w = f2b(ST[mi][3]);
                *(ushort4*)&Plw[l16 * 76 + mi * 16 + quad * 4] = pk;
            }

            float aRow[4];
#pragma unroll
            for (int r = 0; r < 4; r++) aRow[r] = __shfl(alpha, quad * 4 + r);
#pragma unroll
            for (int ni = 0; ni < 8; ni++) {
#pragma unroll
                for (int r = 0; r < 4; r++) Oacc[ni][r] *= aRow[r];
            }

            // O += P V
            bf16x8 Pf[2];
#pragma unroll
            for (int kk = 0; kk < 2; kk++)
                Pf[kk] = *(const bf16x8*)&Plw[l16 * 76 + kk * 32 + quad * 8];
#pragma unroll
            for (int kk = 0; kk < 2; kk++) {
                const int cb = ((kk * 4 + quad) ^ fx) * 8;
#pragma unroll
                for (int ni = 0; ni < 8; ni++) {
                    bf16x8 Vf = *(const bf16x8*)&Vtc[(ni * 16 + l16) * 64 + cb];
                    Oacc[ni] = MFMA_16x16x32_BF16(Pf[kk], Vf, Oacc[ni]);
                }
            }
        }

        // final l: reduce per-lane partials across quads, broadcast to rows
        lrow += __shfl_xor(lrow, 16);
        lrow += __shfl_xor(lrow, 32);
        float inv = 1.0f / lrow;
        float iRow[4];
#pragma unroll
        for (int r = 0; r < 4; r++) iRow[r] = __shfl(inv, quad * 4 + r);

#pragma unroll
        for (int r = 0; r < 4; r++) {
            int t = row0 + quad * 4 + r;
            size_t rowb = ((size_t)(b * 2048 + t)) * 2048 + (size_t)(h * 128);
#pragma unroll
            for (int ni = 0; ni < 8; ni++)
                O[rowb + ni * 16 + l16] = f2b(Oacc[ni][r] * iRow[r]);
        }
    }
}

// ---------------------------------------------------------------------------
extern "C" void kernel_launch(void* const* d_in, const int* in_sizes, int n_in,
                              void* d_out, int out_size, void* d_ws, size_t ws_size,
                              hipStream_t stream) {
    const float* x  = (const float*)d_in[0];
    const float* wq = (const float*)d_in[1];
    const float* wp = (const float*)d_in[2];

    char* ws = (char*)d_ws;
    u16* xb   = (u16*)(ws + 0);            // 16,777,216
    u16* wqb  = (u16*)(ws + 16777216);     // 25,165,824
    u16* wpb  = (u16*)(ws + 41943040);     //  8,388,608
    u16* qkvb = (u16*)(ws + 50331648);     // 50,331,648
    u16* Qr   = (u16*)(ws + 100663296);    // 16,777,216
    u16* Kr   = (u16*)(ws + 117440512);    // 16,777,216
    u16* VTt  = (u16*)(ws + 134217728);    // 16,777,216 (V^T, [B,H,Dh,T])
    u16* Ob   = (u16*)(ws + 50331648);     // overlays qkvb (free after rope/vtrans)
    if (ws_size < 150994944) return;

    cast3<<<2048, 256, 0, stream>>>(x, wq, wp, xb, wqb, wpb);
    gemm_bt<1><<<dim3(48, 32), 256, 0, stream>>>(xb, wqb, qkvb, 4096, 6144, 2048);
    rope_qk<<<4096, 256, 0, stream>>>(qkvb, Qr, Kr);
    vtrans<<<dim3(32, 32), 256, 0, stream>>>(qkvb, VTt);
    attn<<<dim3(16, 32), 256, 0, stream>>>(Qr, Kr, VTt, Ob);
    gemm_bt<0><<<dim3(16, 32), 256, 0, stream>>>(Ob, wpb, (float*)d_out, 4096, 2048, 2048);
}